// Round 1
// baseline (83.943 us; speedup 1.0000x reference)
//
#include <hip/hip_runtime.h>

// BSplineActivation: y = sum_i B_i^3(clip(x,-1,1)) * c_i over a 12-knot
// (nearly) uniform grid on [-1.2, 1.2]. GRID_SIZE=5, ORDER=3 -> 8 bases,
// 11 intervals. For uniform knots, on interval j the result is a single
// cubic in u = (x - g0)/h - j:
//   y = A_j + B_j*u + C_j*u^2 + D_j*u^3
// with A..D linear combos of (zero-padded) coefficients c[j-3..j].
// Table (11 x float4) built once per block in LDS; per-element work is
// clamp + fma + floor + ds_read_b128 + 3 fma. Memory-roofline kernel.

__global__ void __launch_bounds__(256) bspline_act_kernel(
    const float* __restrict__ x,
    const float* __restrict__ grid,
    const float* __restrict__ coeff,
    float* __restrict__ out,
    int n4)
{
    __shared__ float4 table[11];
    __shared__ float s_g0, s_invh;

    const int tid = threadIdx.x;

    if (tid == 0) {
        float g0  = grid[0];
        float g11 = grid[11];
        float h   = (g11 - g0) * (1.0f / 11.0f);
        s_g0   = g0;
        s_invh = 1.0f / h;
    }
    if (tid < 11) {
        const int j = tid;
        float c[4];
#pragma unroll
        for (int m = 0; m < 4; ++m) {
            int idx = j + m - 3;              // basis index j-3+m
            c[m] = (idx >= 0 && idx < 8) ? coeff[idx] : 0.0f;
        }
        const float k6 = 1.0f / 6.0f;
        float A = (c[0] + 4.0f * c[1] + c[2]) * k6;
        float B = (3.0f * (c[2] - c[0])) * k6;
        float C = (3.0f * c[0] - 6.0f * c[1] + 3.0f * c[2]) * k6;
        float D = (-c[0] + 3.0f * c[1] - 3.0f * c[2] + c[3]) * k6;
        table[j] = make_float4(A, B, C, D);
    }
    __syncthreads();

    const float g0   = s_g0;
    const float invh = s_invh;

    const float4* __restrict__ x4 = (const float4*)x;
    float4* __restrict__ o4 = (float4*)out;

    const int stride = gridDim.x * blockDim.x;
    for (int i = blockIdx.x * blockDim.x + tid; i < n4; i += stride) {
        float4 v = x4[i];
        float4 r;
        float* vp = &v.x;
        float* rp = &r.x;
#pragma unroll
        for (int e = 0; e < 4; ++e) {
            float xc = fminf(fmaxf(vp[e], -1.0f), 1.0f);
            float t  = (xc - g0) * invh;       // grid-units position, ~[0.92, 10.09]
            int   j  = (int)t;                 // t >= 0 -> trunc == floor
            j = j < 0 ? 0 : (j > 10 ? 10 : j);
            float u  = t - (float)j;
            float4 p = table[j];
            rp[e] = ((p.w * u + p.z) * u + p.y) * u + p.x;
        }
        o4[i] = r;
    }
}

extern "C" void kernel_launch(void* const* d_in, const int* in_sizes, int n_in,
                              void* d_out, int out_size, void* d_ws, size_t ws_size,
                              hipStream_t stream) {
    const float* x     = (const float*)d_in[0];
    const float* grid  = (const float*)d_in[1];
    const float* coeff = (const float*)d_in[2];
    float* out = (float*)d_out;

    const int n  = in_sizes[0];          // 2048*4096 = 8388608, divisible by 4
    const int n4 = n >> 2;               // 2097152 float4 elements

    const int block = 256;
    const int blocks = 2048;             // 8 blocks/CU, 4 float4 iters/thread
    bspline_act_kernel<<<blocks, block, 0, stream>>>(x, grid, coeff, out, n4);
}